// Round 7
// baseline (457.353 us; speedup 1.0000x reference)
//
#include <hip/hip_runtime.h>
#include <cstdint>
#include <cstddef>

// NOBlock: B=4, N=2048, V=1, M=64 (8x8), C=128, rank 8, GRP=4.
// One block = one output group (4 consecutive tokens). 256 threads, 4 blocks/CU.
//
// All-token-batched pipeline, 7 barriers total, ping-pong 8KB LDS buffers:
//   P1 per token: residual (global->regs) + stage A (x rows from global, if2T
//      from LDS, both b128) -> t1[4][64][8] in buf0
//   P2 B1: contract d with if1  -> t2[4][E][a][F]  in buf1
//   P3 B2: contract a with if0  -> z [4][D][E][F]  in buf0
//   P4 core: z2[4][ABC] = core . z (one pass over 1MB core for 4 tokens) -> buf1
//   P5 D1: contract A with of0T -> u [4][o][Bq][Cr] in buf0
//   P6 D2: contract B with of1T -> v [4][p][o][Cr]  in buf1
//   P7 D3: h = v . of2 rows (regs) summed over tokens into acc, * winv, store.

__launch_bounds__(256, 4)
__global__ void noblock_kernel(const float* __restrict__ x,
                               const float* __restrict__ core,
                               const float* __restrict__ of0,
                               const float* __restrict__ of1,
                               const float* __restrict__ of2,
                               const float* __restrict__ if0,
                               const float* __restrict__ if1,
                               const float* __restrict__ if2,
                               const int* __restrict__ mask,
                               float* __restrict__ out)
{
    __shared__ float buf0[2048];        // t1 / z / u
    __shared__ float buf1[2048];        // t2 / z2 / v
    __shared__ float s_if2T[8 * 132];   // transposed, padded: [F][e]
    __shared__ float s_if0[64], s_if1[64];
    __shared__ float s_of0T[64], s_of1T[64];   // transposed: [A][o], [B][p]
    __shared__ float s_winv[64];

    const int t = threadIdx.x;
    const int blk = blockIdx.x;
    const long tok0 = (long)blk * 4;

    // ---- P0: stage factors (if2 transposed), winv ----
    for (int i = t; i < 1024; i += 256) {
        const int e = i & 127, F = i >> 7;
        s_if2T[F * 132 + e] = if2[e * 8 + F];
    }
    if (t < 64) {
        s_if0[t] = if0[t];
        s_if1[t] = if1[t];
        s_of0T[t] = of0[(t & 7) * 8 + (t >> 3)];   // [A*8+o] = of0[o][A]
        s_of1T[t] = of1[(t & 7) * 8 + (t >> 3)];   // [B*8+p] = of1[p][B]
        const int* mp = mask + (size_t)tok0 * 64 + t;
        int cnt = 0;
        #pragma unroll
        for (int j = 0; j < 4; ++j) cnt += (mp[j * 64] == 0) ? 1 : 0;
        s_winv[t] = cnt ? 1.0f / (float)cnt : 0.0f;
    }

    float4 acc[8];
    #pragma unroll
    for (int i = 0; i < 8; ++i) acc[i] = make_float4(0.f, 0.f, 0.f, 0.f);

    __syncthreads();

    // ---- P1: residual + stage A for all 4 tokens (no internal barriers) ----
    for (int j = 0; j < 4; ++j) {
        const float* xg = x + (size_t)(tok0 + j) * 8192;
        const float4* xg4 = (const float4*)xg;
        #pragma unroll
        for (int i = 0; i < 8; ++i) {
            const float4 v = xg4[t + 256 * i];
            acc[i].x += v.x; acc[i].y += v.y; acc[i].z += v.z; acc[i].w += v.w;
        }
        #pragma unroll
        for (int h = 0; h < 2; ++h) {
            const int id = t + h * 256;
            const int m = id >> 3, F = id & 7;
            const float4* xr = (const float4*)(xg + m * 128);     // L1/L2-hot re-read
            const float4* wr = (const float4*)(s_if2T + F * 132);
            float s0 = 0.f, s1 = 0.f;
            #pragma unroll 4
            for (int e4 = 0; e4 < 32; e4 += 2) {
                const float4 a  = xr[e4],     b  = wr[e4];
                const float4 a2 = xr[e4 + 1], b2 = wr[e4 + 1];
                s0 = fmaf(a.w,  b.w,  fmaf(a.z,  b.z,  fmaf(a.y,  b.y,  fmaf(a.x,  b.x,  s0))));
                s1 = fmaf(a2.w, b2.w, fmaf(a2.z, b2.z, fmaf(a2.y, b2.y, fmaf(a2.x, b2.x, s1))));
            }
            buf0[j * 512 + id] = s0 + s1;   // t1[j][m][F]
        }
    }
    __syncthreads();

    // ---- P2: B1  t2[j][E][a][F] = sum_d t1[j][a][d][F] * if1[d][E] ----
    {
        const int j = t >> 6, a = (t >> 3) & 7, F = t & 7;
        float s[8];
        #pragma unroll
        for (int E = 0; E < 8; ++E) s[E] = 0.f;
        #pragma unroll
        for (int d0 = 0; d0 < 8; ++d0) {
            const int d = (d0 + a) & 7;                       // stagger: 2-way banks
            const float tv = buf0[j * 512 + a * 64 + d * 8 + F];
            const float4 w0 = *(const float4*)(s_if1 + d * 8);
            const float4 w1 = *(const float4*)(s_if1 + d * 8 + 4);
            s[0] = fmaf(tv, w0.x, s[0]); s[1] = fmaf(tv, w0.y, s[1]);
            s[2] = fmaf(tv, w0.z, s[2]); s[3] = fmaf(tv, w0.w, s[3]);
            s[4] = fmaf(tv, w1.x, s[4]); s[5] = fmaf(tv, w1.y, s[5]);
            s[6] = fmaf(tv, w1.z, s[6]); s[7] = fmaf(tv, w1.w, s[7]);
        }
        #pragma unroll
        for (int E = 0; E < 8; ++E) buf1[j * 512 + E * 64 + a * 8 + F] = s[E];
    }
    __syncthreads();

    // ---- P3: B2  z[j][D][E][F] = sum_a t2[j][E][a][F] * if0[a][D] ----
    {
        const int j = t >> 6, E = (t >> 3) & 7, F = t & 7;
        float s[8];
        #pragma unroll
        for (int D = 0; D < 8; ++D) s[D] = 0.f;
        #pragma unroll
        for (int a0 = 0; a0 < 8; ++a0) {
            const int a = (a0 + E) & 7;
            const float tv = buf1[j * 512 + E * 64 + a * 8 + F];
            const float4 w0 = *(const float4*)(s_if0 + a * 8);
            const float4 w1 = *(const float4*)(s_if0 + a * 8 + 4);
            s[0] = fmaf(tv, w0.x, s[0]); s[1] = fmaf(tv, w0.y, s[1]);
            s[2] = fmaf(tv, w0.z, s[2]); s[3] = fmaf(tv, w0.w, s[3]);
            s[4] = fmaf(tv, w1.x, s[4]); s[5] = fmaf(tv, w1.y, s[5]);
            s[6] = fmaf(tv, w1.z, s[6]); s[7] = fmaf(tv, w1.w, s[7]);
        }
        #pragma unroll
        for (int D = 0; D < 8; ++D) buf0[j * 512 + D * 64 + E * 8 + F] = s[D];
    }
    __syncthreads();

    // ---- P4: core contraction, one pass over core for 4 tokens ----
    {
        const float4* cr0 = (const float4*)(core + (size_t)t * 512);
        const float4* cr1 = (const float4*)(core + (size_t)(t + 256) * 512);
        const float4* z4 = (const float4*)buf0;
        float a0[4] = {0, 0, 0, 0}, a1[4] = {0, 0, 0, 0};
        for (int kk = 0; kk < 128; ++kk) {
            const float4 c0 = cr0[kk], c1 = cr1[kk];
            #pragma unroll
            for (int j = 0; j < 4; ++j) {
                const float4 zv = z4[j * 128 + kk];   // broadcast
                a0[j] = fmaf(c0.w, zv.w, fmaf(c0.z, zv.z, fmaf(c0.y, zv.y, fmaf(c0.x, zv.x, a0[j]))));
                a1[j] = fmaf(c1.w, zv.w, fmaf(c1.z, zv.z, fmaf(c1.y, zv.y, fmaf(c1.x, zv.x, a1[j]))));
            }
        }
        // buf1 (t2) is dead since P3's barrier; safe to overwrite without sync
        #pragma unroll
        for (int j = 0; j < 4; ++j) {
            buf1[j * 512 + t]       = a0[j];
            buf1[j * 512 + t + 256] = a1[j];
        }
    }
    __syncthreads();

    // ---- P5: D1  u[j][o][Bq][Cr] = sum_A z2[j][A][Bq][Cr] * of0[o][A] ----
    {
        const int j = t >> 6, Bq = (t >> 3) & 7, Cr = t & 7;
        float s[8];
        #pragma unroll
        for (int o = 0; o < 8; ++o) s[o] = 0.f;
        #pragma unroll
        for (int A = 0; A < 8; ++A) {
            const float tv = buf1[j * 512 + A * 64 + Bq * 8 + Cr];
            const float4 w0 = *(const float4*)(s_of0T + A * 8);   // uniform: broadcast
            const float4 w1 = *(const float4*)(s_of0T + A * 8 + 4);
            s[0] = fmaf(tv, w0.x, s[0]); s[1] = fmaf(tv, w0.y, s[1]);
            s[2] = fmaf(tv, w0.z, s[2]); s[3] = fmaf(tv, w0.w, s[3]);
            s[4] = fmaf(tv, w1.x, s[4]); s[5] = fmaf(tv, w1.y, s[5]);
            s[6] = fmaf(tv, w1.z, s[6]); s[7] = fmaf(tv, w1.w, s[7]);
        }
        #pragma unroll
        for (int o = 0; o < 8; ++o) buf0[j * 512 + o * 64 + Bq * 8 + Cr] = s[o];
    }
    __syncthreads();

    // ---- P6: D2  v[j][p][o][Cr] = sum_B u[j][o][B][Cr] * of1[p][B] ----
    {
        const int j = t >> 6, o = (t >> 3) & 7, Cr = t & 7;
        float s[8];
        #pragma unroll
        for (int p = 0; p < 8; ++p) s[p] = 0.f;
        #pragma unroll
        for (int B0 = 0; B0 < 8; ++B0) {
            const int Bq = (B0 + o) & 7;                      // stagger: 2-way banks
            const float tv = buf0[j * 512 + o * 64 + Bq * 8 + Cr];
            const float4 w0 = *(const float4*)(s_of1T + Bq * 8);
            const float4 w1 = *(const float4*)(s_of1T + Bq * 8 + 4);
            s[0] = fmaf(tv, w0.x, s[0]); s[1] = fmaf(tv, w0.y, s[1]);
            s[2] = fmaf(tv, w0.z, s[2]); s[3] = fmaf(tv, w0.w, s[3]);
            s[4] = fmaf(tv, w1.x, s[4]); s[5] = fmaf(tv, w1.y, s[5]);
            s[6] = fmaf(tv, w1.z, s[6]); s[7] = fmaf(tv, w1.w, s[7]);
        }
        #pragma unroll
        for (int p = 0; p < 8; ++p) buf1[j * 512 + p * 64 + o * 8 + Cr] = s[p];
    }
    __syncthreads();

    // ---- P7: D3  acc += sum_Cr v[j][m][Cr] * of2[q][Cr]; out = acc * winv ----
    {
        float4 w[4][2];
        const int cc = (4 * t) & 127;            // 4 channels owned per float4
        #pragma unroll
        for (int c = 0; c < 4; ++c) {
            w[c][0] = *(const float4*)(of2 + (cc + c) * 8);
            w[c][1] = *(const float4*)(of2 + (cc + c) * 8 + 4);
        }
        float4* out4 = (float4*)out + (size_t)blk * 2048;
        #pragma unroll
        for (int i = 0; i < 8; ++i) {
            const int m = (t >> 5) + 8 * i;
            const int o = m >> 3, p = m & 7;
            const float wv = s_winv[m];
            #pragma unroll
            for (int j = 0; j < 4; ++j) {
                const int base = j * 512 + p * 64 + o * 8;
                const float4 v0 = *(const float4*)(buf1 + base);      // broadcast
                const float4 v1 = *(const float4*)(buf1 + base + 4);
                acc[i].x = fmaf(v1.w, w[0][1].w, fmaf(v1.z, w[0][1].z, fmaf(v1.y, w[0][1].y, fmaf(v1.x, w[0][1].x,
                           fmaf(v0.w, w[0][0].w, fmaf(v0.z, w[0][0].z, fmaf(v0.y, w[0][0].y, fmaf(v0.x, w[0][0].x, acc[i].x))))))));
                acc[i].y = fmaf(v1.w, w[1][1].w, fmaf(v1.z, w[1][1].z, fmaf(v1.y, w[1][1].y, fmaf(v1.x, w[1][1].x,
                           fmaf(v0.w, w[1][0].w, fmaf(v0.z, w[1][0].z, fmaf(v0.y, w[1][0].y, fmaf(v0.x, w[1][0].x, acc[i].y))))))));
                acc[i].z = fmaf(v1.w, w[2][1].w, fmaf(v1.z, w[2][1].z, fmaf(v1.y, w[2][1].y, fmaf(v1.x, w[2][1].x,
                           fmaf(v0.w, w[2][0].w, fmaf(v0.z, w[2][0].z, fmaf(v0.y, w[2][0].y, fmaf(v0.x, w[2][0].x, acc[i].z))))))));
                acc[i].w = fmaf(v1.w, w[3][1].w, fmaf(v1.z, w[3][1].z, fmaf(v1.y, w[3][1].y, fmaf(v1.x, w[3][1].x,
                           fmaf(v0.w, w[3][0].w, fmaf(v0.z, w[3][0].z, fmaf(v0.y, w[3][0].y, fmaf(v0.x, w[3][0].x, acc[i].w))))))));
            }
            float4 r;
            r.x = acc[i].x * wv; r.y = acc[i].y * wv;
            r.z = acc[i].z * wv; r.w = acc[i].w * wv;
            out4[t + 256 * i] = r;
        }
    }
}

extern "C" void kernel_launch(void* const* d_in, const int* in_sizes, int n_in,
                              void* d_out, int out_size, void* d_ws, size_t ws_size,
                              hipStream_t stream) {
    const float* x    = (const float*)d_in[0];
    const float* core = (const float*)d_in[1];
    const float* of0  = (const float*)d_in[2];
    const float* of1  = (const float*)d_in[3];
    const float* of2  = (const float*)d_in[4];
    const float* if0  = (const float*)d_in[5];
    const float* if1  = (const float*)d_in[6];
    const float* if2  = (const float*)d_in[7];
    const int* mask   = (const int*)d_in[8];
    float* out = (float*)d_out;

    noblock_kernel<<<dim3(2048), dim3(256), 0, stream>>>(
        x, core, of0, of1, of2, if0, if1, if2, mask, out);
}

// Round 8
// 200.454 us; speedup vs baseline: 2.2816x; 2.2816x over previous
//
#include <hip/hip_runtime.h>
#include <cstdint>
#include <cstddef>

// NOBlock: B=4, N=2048, V=1, M=64 (8x8), C=128, rank 8, GRP=4.
//
// KEY ALGEBRA: the op is linear in x and the mask only sets the divisor w
// (all 4 group members are always summed). So
//   out = winv * (Tucker(sum_j x_j) + sum_j x_j)
// -> ONE Tucker transform per GROUP (2048) instead of per token (8192): 4x
// less compute, 4x fewer core passes. Memory floor: x 268MB + out 67MB.
//
// One block = 2 groups (8 contiguous tokens). 256 threads, 3 blocks/CU.
//   P0: stage factors (if2 transposed, padded), winv per group-cell
//   P1: load all 8 tokens coalesced (64 f4/thread in flight), sum per group
//       -> acc[2][8] regs (doubles as residual)
//   per group g: write xsum->xs(132-pad); A: t1=xs*if2T (b128 dots);
//                B1: t2 (d->E); B2: zz[g] (a->D)
//   C: z2[g] = core(512x512) . zz[g]  — one pass over 1MB core for 2 groups
//   per group g: D1: u=z2*of0T; D2: v=u*of1T; D3: h=v.of2 + acc[g], *winv, store

__device__ __forceinline__ float dot4(const float4 a, const float4 b, float s) {
    return fmaf(a.w, b.w, fmaf(a.z, b.z, fmaf(a.y, b.y, fmaf(a.x, b.x, s))));
}

__launch_bounds__(256, 3)
__global__ void noblock_kernel(const float* __restrict__ x,
                               const float* __restrict__ core,
                               const float* __restrict__ of0,
                               const float* __restrict__ of1,
                               const float* __restrict__ of2,
                               const float* __restrict__ if0,
                               const float* __restrict__ if1,
                               const float* __restrict__ if2,
                               const int* __restrict__ mask,
                               float* __restrict__ out)
{
    __shared__ float xs[64 * 132];      // 33.8 KB xsum tile (reused per group)
    __shared__ float t1[512];
    __shared__ float t2[512];
    __shared__ float zz[2 * 512];       // z per group
    __shared__ float z2[2 * 512];       // core output per group
    __shared__ float s_if2T[8 * 132];   // [F][e], padded
    __shared__ float s_if0[64], s_if1[64];
    __shared__ float s_of0T[64], s_of1T[64];   // [A][o], [B][p]
    __shared__ float s_winv[128];       // [g][m]

    const int t = threadIdx.x;
    const int blk = blockIdx.x;

    // ---- P0: stage factors + winv ----
    for (int i = t; i < 1024; i += 256) {
        const int e = i & 127, F = i >> 7;
        s_if2T[F * 132 + e] = if2[e * 8 + F];
    }
    if (t < 64) {
        s_if0[t] = if0[t];
        s_if1[t] = if1[t];
        s_of0T[t] = of0[(t & 7) * 8 + (t >> 3)];
        s_of1T[t] = of1[(t & 7) * 8 + (t >> 3)];
    }
    if (t < 128) {
        const int g = t >> 6, mm = t & 63;
        const int* mp = mask + ((size_t)(blk * 2 + g) * 4) * 64 + mm;
        int cnt = 0;
        #pragma unroll
        for (int j = 0; j < 4; ++j) cnt += (mp[j * 64] == 0) ? 1 : 0;
        s_winv[t] = cnt ? 1.0f / (float)cnt : 0.0f;
    }

    // ---- P1: load 8 tokens (256 KB contiguous), sum per group into regs ----
    float4 acc[2][8];
    const float4* xg4 = (const float4*)(x + (size_t)blk * 8 * 8192);
    #pragma unroll
    for (int g = 0; g < 2; ++g)
        #pragma unroll
        for (int i = 0; i < 8; ++i)
            acc[g][i] = xg4[(size_t)(g * 4) * 2048 + t + 256 * i];
    #pragma unroll
    for (int j = 1; j < 4; ++j)
        #pragma unroll
        for (int g = 0; g < 2; ++g)
            #pragma unroll
            for (int i = 0; i < 8; ++i) {
                const float4 v = xg4[(size_t)(g * 4 + j) * 2048 + t + 256 * i];
                acc[g][i].x += v.x; acc[g][i].y += v.y;
                acc[g][i].z += v.z; acc[g][i].w += v.w;
            }

    // ---- per-group in-projection ----
    #pragma unroll
    for (int g = 0; g < 2; ++g) {
        // write xsum -> xs (padded rows; b128 stores, structural-min banking)
        #pragma unroll
        for (int i = 0; i < 8; ++i) {
            const int f4i = t + 256 * i;
            *(float4*)&xs[(f4i >> 5) * 132 + (f4i & 31) * 4] = acc[g][i];
        }
        __syncthreads();   // (1st iter: also guards P0 staging)

        // A: t1[m*8+F] = sum_e xs[m][e] * if2T[F][e]  — all-b128 dots
        #pragma unroll
        for (int h = 0; h < 2; ++h) {
            const int id = t + 256 * h;
            const int m = id >> 3, F = id & 7;
            const float4* xr = (const float4*)(xs + m * 132);
            const float4* wr = (const float4*)(s_if2T + F * 132);
            float s0 = 0.f, s1 = 0.f;
            #pragma unroll
            for (int e4 = 0; e4 < 32; e4 += 2) {
                s0 = dot4(xr[e4],     wr[e4],     s0);
                s1 = dot4(xr[e4 + 1], wr[e4 + 1], s1);
            }
            t1[id] = s0 + s1;
        }
        __syncthreads();

        // B1: t2[E*64+a*8+F] = sum_d t1[a*64+d*8+F] * if1[d][E]
        #pragma unroll
        for (int h = 0; h < 2; ++h) {
            const int id = t + 256 * h;
            const int E = id >> 6, a = (id >> 3) & 7, F = id & 7;
            float s = 0.f;
            #pragma unroll
            for (int d0 = 0; d0 < 8; ++d0) {
                const int d = (d0 + a) & 7;           // stagger: 2-way banks
                s = fmaf(t1[a * 64 + d * 8 + F], s_if1[d * 8 + E], s);
            }
            t2[id] = s;
        }
        __syncthreads();

        // B2: zz[g][D*64+E*8+F] = sum_a t2[E*64+a*8+F] * if0[a][D]
        #pragma unroll
        for (int h = 0; h < 2; ++h) {
            const int id = t + 256 * h;
            const int D = id >> 6, E = (id >> 3) & 7, F = id & 7;
            float s = 0.f;
            #pragma unroll
            for (int a0 = 0; a0 < 8; ++a0) {
                const int a = (a0 + E) & 7;           // stagger: 2-way banks
                s = fmaf(t2[E * 64 + a * 8 + F], s_if0[a * 8 + D], s);
            }
            zz[g * 512 + id] = s;
        }
        __syncthreads();
    }

    // ---- C: z2[g] = core . zz[g], one streaming pass over the 1MB core ----
    {
        const float4* cr0 = (const float4*)(core + (size_t)t * 512);
        const float4* cr1 = (const float4*)(core + (size_t)(t + 256) * 512);
        const float4* z4 = (const float4*)zz;
        float a0[2] = {0.f, 0.f}, a1[2] = {0.f, 0.f};
        for (int kk = 0; kk < 128; ++kk) {
            const float4 c0 = cr0[kk], c1 = cr1[kk];
            #pragma unroll
            for (int g = 0; g < 2; ++g) {
                const float4 zv = z4[g * 128 + kk];   // broadcast
                a0[g] = dot4(c0, zv, a0[g]);
                a1[g] = dot4(c1, zv, a1[g]);
            }
        }
        #pragma unroll
        for (int g = 0; g < 2; ++g) {
            z2[g * 512 + t]       = a0[g];
            z2[g * 512 + t + 256] = a1[g];
        }
    }
    __syncthreads();

    // of2 rows for this thread's 4 channels (L1-hot global)
    float4 w[4][2];
    {
        const int cc = (4 * t) & 127;
        #pragma unroll
        for (int c = 0; c < 4; ++c) {
            w[c][0] = *(const float4*)(of2 + (cc + c) * 8);
            w[c][1] = *(const float4*)(of2 + (cc + c) * 8 + 4);
        }
    }

    // ---- per-group out-projection + residual + winv + store ----
    float4* out4 = (float4*)out;
    #pragma unroll
    for (int g = 0; g < 2; ++g) {
        // D1: t1[o*64+Bq*8+Cr] = sum_A z2[g][A*64+Bq*8+Cr] * of0T[A][o]
        #pragma unroll
        for (int h = 0; h < 2; ++h) {
            const int id = t + 256 * h;
            const int o = id >> 6, Bq = (id >> 3) & 7, Cr = id & 7;
            float s = 0.f;
            #pragma unroll
            for (int A = 0; A < 8; ++A)
                s = fmaf(z2[g * 512 + A * 64 + Bq * 8 + Cr], s_of0T[A * 8 + o], s);
            t1[id] = s;
        }
        __syncthreads();

        // D2: t2[p*64+o*8+Cr] = sum_B t1[o*64+B*8+Cr] * of1T[B][p]
        #pragma unroll
        for (int h = 0; h < 2; ++h) {
            const int id = t + 256 * h;
            const int p = id >> 6, o = (id >> 3) & 7, Cr = id & 7;
            float s = 0.f;
            #pragma unroll
            for (int B0 = 0; B0 < 8; ++B0) {
                const int Bq = (B0 + o) & 7;          // stagger: 2-way banks
                s = fmaf(t1[o * 64 + Bq * 8 + Cr], s_of1T[Bq * 8 + p], s);
            }
            t2[id] = s;
        }
        __syncthreads();

        // D3: h = v . of2 + residual; * winv; store
        #pragma unroll
        for (int i = 0; i < 8; ++i) {
            const int m = (t >> 5) + 8 * i;
            const int o = m >> 3, p = m & 7;
            const float wv = s_winv[g * 64 + m];
            const int base = p * 64 + o * 8;
            const float4 v0 = *(const float4*)(t2 + base);      // broadcast
            const float4 v1 = *(const float4*)(t2 + base + 4);
            float4 r;
            r.x = dot4(v1, w[0][1], dot4(v0, w[0][0], acc[g][i].x));
            r.y = dot4(v1, w[1][1], dot4(v0, w[1][0], acc[g][i].y));
            r.z = dot4(v1, w[2][1], dot4(v0, w[2][0], acc[g][i].z));
            r.w = dot4(v1, w[3][1], dot4(v0, w[3][0], acc[g][i].w));
            r.x *= wv; r.y *= wv; r.z *= wv; r.w *= wv;
            out4[(size_t)(blk * 2 + g) * 2048 + t + 256 * i] = r;
        }
        __syncthreads();   // before next group's D1 overwrites t1
    }
}

extern "C" void kernel_launch(void* const* d_in, const int* in_sizes, int n_in,
                              void* d_out, int out_size, void* d_ws, size_t ws_size,
                              hipStream_t stream) {
    const float* x    = (const float*)d_in[0];
    const float* core = (const float*)d_in[1];
    const float* of0  = (const float*)d_in[2];
    const float* of1  = (const float*)d_in[3];
    const float* of2  = (const float*)d_in[4];
    const float* if0  = (const float*)d_in[5];
    const float* if1  = (const float*)d_in[6];
    const float* if2  = (const float*)d_in[7];
    const int* mask   = (const int*)d_in[8];
    float* out = (float*)d_out;

    noblock_kernel<<<dim3(1024), dim3(256), 0, stream>>>(
        x, core, of0, of1, of2, if0, if1, if2, mask, out);
}

// Round 9
// 156.655 us; speedup vs baseline: 2.9195x; 1.2796x over previous
//
#include <hip/hip_runtime.h>
#include <cstdint>
#include <cstddef>

// NOBlock: B=4, N=2048, V=1, M=64 (8x8), C=128, rank 8, GRP=4.
//
// ALGEBRA: op is linear in x; mask only sets the divisor w (all 4 group
// members are always summed):  out = winv * (Tucker(sum_j x_j) + sum_j x_j)
// -> ONE Tucker transform per GROUP (2048 total). Memory floor ~53us.
//
// ROUND 9 FIX: stage C (z2 = core . z) previously had each thread read its
// own 2KB-strided core row -> 64 cache lines per wave load, zero coalescing,
// L1/L2 thrash (the dominant stall: VALUBusy 10%, HBM 10%). Now a tiny
// pre-kernel transposes core into d_ws as cT[k4][r] (float4 of 4 k's), so
// lane t reads cT[k4*512+t]: fully coalesced 1KB/wave-instr L2 streaming,
// 8 independent FMA chains for MLP.

__device__ __forceinline__ float dot4(const float4 a, const float4 b, float s) {
    return fmaf(a.w, b.w, fmaf(a.z, b.z, fmaf(a.y, b.y, fmaf(a.x, b.x, s))));
}

// core[r][k] (512x512) -> cT[k>>2][r] as float4 over k&3. Coalesced stores.
__global__ void transpose_core(const float* __restrict__ core,
                               float* __restrict__ coreT) {
    const int tid = blockIdx.x * 256 + threadIdx.x;   // 0..65535
    const int r = tid & 511, k4 = tid >> 9;
    ((float4*)coreT)[(size_t)k4 * 512 + r] =
        ((const float4*)core)[(size_t)r * 128 + k4];
}

template<bool TR>
__launch_bounds__(256, 3)
__global__ void noblock_kernel(const float* __restrict__ x,
                               const float* __restrict__ core,
                               const float* __restrict__ coreT,
                               const float* __restrict__ of0,
                               const float* __restrict__ of1,
                               const float* __restrict__ of2,
                               const float* __restrict__ if0,
                               const float* __restrict__ if1,
                               const float* __restrict__ if2,
                               const int* __restrict__ mask,
                               float* __restrict__ out)
{
    __shared__ float xs[64 * 132];      // 33.8 KB xsum tile (reused per group)
    __shared__ float t1[512];
    __shared__ float t2[512];
    __shared__ float zz[2 * 512];       // z per group
    __shared__ float z2[2 * 512];       // core output per group
    __shared__ float s_if2T[8 * 132];   // [F][e], padded
    __shared__ float s_if0[64], s_if1[64];
    __shared__ float s_of0T[64], s_of1T[64];   // [A][o], [B][p]
    __shared__ float s_winv[128];       // [g][m]

    const int t = threadIdx.x;
    const int blk = blockIdx.x;

    // ---- P0: stage factors + winv ----
    for (int i = t; i < 1024; i += 256) {
        const int e = i & 127, F = i >> 7;
        s_if2T[F * 132 + e] = if2[e * 8 + F];
    }
    if (t < 64) {
        s_if0[t] = if0[t];
        s_if1[t] = if1[t];
        s_of0T[t] = of0[(t & 7) * 8 + (t >> 3)];
        s_of1T[t] = of1[(t & 7) * 8 + (t >> 3)];
    }
    if (t < 128) {
        const int g = t >> 6, mm = t & 63;
        const int* mp = mask + ((size_t)(blk * 2 + g) * 4) * 64 + mm;
        int cnt = 0;
        #pragma unroll
        for (int j = 0; j < 4; ++j) cnt += (mp[j * 64] == 0) ? 1 : 0;
        s_winv[t] = cnt ? 1.0f / (float)cnt : 0.0f;
    }

    // ---- P1: load 8 tokens (256 KB contiguous), sum per group into regs ----
    // batched 8-wide temp loads for HBM MLP
    float4 acc[2][8];
    const float4* xg4 = (const float4*)(x + (size_t)blk * 8 * 8192);
    #pragma unroll
    for (int g = 0; g < 2; ++g)
        #pragma unroll
        for (int i = 0; i < 8; ++i)
            acc[g][i] = xg4[(size_t)(g * 4) * 2048 + t + 256 * i];
    #pragma unroll
    for (int j = 1; j < 4; ++j) {
        #pragma unroll
        for (int g = 0; g < 2; ++g) {
            float4 v[8];
            #pragma unroll
            for (int i = 0; i < 8; ++i)
                v[i] = xg4[(size_t)(g * 4 + j) * 2048 + t + 256 * i];
            #pragma unroll
            for (int i = 0; i < 8; ++i) {
                acc[g][i].x += v[i].x; acc[g][i].y += v[i].y;
                acc[g][i].z += v[i].z; acc[g][i].w += v[i].w;
            }
        }
    }

    // ---- per-group in-projection ----
    #pragma unroll
    for (int g = 0; g < 2; ++g) {
        // write xsum -> xs (padded rows)
        #pragma unroll
        for (int i = 0; i < 8; ++i) {
            const int f4i = t + 256 * i;
            *(float4*)&xs[(f4i >> 5) * 132 + (f4i & 31) * 4] = acc[g][i];
        }
        __syncthreads();   // (1st iter: also guards P0 staging)

        // A: t1[m*8+F] = sum_e xs[m][e] * if2T[F][e]  — all-b128 dots
        #pragma unroll
        for (int h = 0; h < 2; ++h) {
            const int id = t + 256 * h;
            const int m = id >> 3, F = id & 7;
            const float4* xr = (const float4*)(xs + m * 132);
            const float4* wr = (const float4*)(s_if2T + F * 132);
            float s0 = 0.f, s1 = 0.f;
            #pragma unroll
            for (int e4 = 0; e4 < 32; e4 += 2) {
                s0 = dot4(xr[e4],     wr[e4],     s0);
                s1 = dot4(xr[e4 + 1], wr[e4 + 1], s1);
            }
            t1[id] = s0 + s1;
        }
        __syncthreads();

        // B1: t2[E*64+a*8+F] = sum_d t1[a*64+d*8+F] * if1[d][E]
        #pragma unroll
        for (int h = 0; h < 2; ++h) {
            const int id = t + 256 * h;
            const int E = id >> 6, a = (id >> 3) & 7, F = id & 7;
            float s = 0.f;
            #pragma unroll
            for (int d0 = 0; d0 < 8; ++d0) {
                const int d = (d0 + a) & 7;           // stagger: 2-way banks
                s = fmaf(t1[a * 64 + d * 8 + F], s_if1[d * 8 + E], s);
            }
            t2[id] = s;
        }
        __syncthreads();

        // B2: zz[g][D*64+E*8+F] = sum_a t2[E*64+a*8+F] * if0[a][D]
        #pragma unroll
        for (int h = 0; h < 2; ++h) {
            const int id = t + 256 * h;
            const int D = id >> 6, E = (id >> 3) & 7, F = id & 7;
            float s = 0.f;
            #pragma unroll
            for (int a0 = 0; a0 < 8; ++a0) {
                const int a = (a0 + E) & 7;           // stagger: 2-way banks
                s = fmaf(t2[E * 64 + a * 8 + F], s_if0[a * 8 + D], s);
            }
            zz[g * 512 + id] = s;
        }
        __syncthreads();
    }

    // ---- C: z2[g][r] = sum_k core[r][k] * zz[g][k] ----
    if (TR) {
        // coalesced: cT[k4*512 + r], lane t reads consecutive float4s.
        // 8 independent accumulator chains (even/odd k4 x 2 rows x 2 groups).
        const float4* cT = (const float4*)coreT;
        const float4* z4 = (const float4*)zz;   // [g*128 + k4]
        float a00 = 0.f, a01 = 0.f, a10 = 0.f, a11 = 0.f;
        float b00 = 0.f, b01 = 0.f, b10 = 0.f, b11 = 0.f;
        #pragma unroll 2
        for (int k4 = 0; k4 < 128; k4 += 2) {
            const float4 c0  = cT[(size_t)k4 * 512 + t];
            const float4 c1  = cT[(size_t)k4 * 512 + t + 256];
            const float4 c0b = cT[(size_t)(k4 + 1) * 512 + t];
            const float4 c1b = cT[(size_t)(k4 + 1) * 512 + t + 256];
            const float4 z0  = z4[k4],     z1  = z4[128 + k4];
            const float4 z0b = z4[k4 + 1], z1b = z4[128 + k4 + 1];
            a00 = dot4(c0,  z0,  a00);  a01 = dot4(c0,  z1,  a01);
            a10 = dot4(c1,  z0,  a10);  a11 = dot4(c1,  z1,  a11);
            b00 = dot4(c0b, z0b, b00);  b01 = dot4(c0b, z1b, b01);
            b10 = dot4(c1b, z0b, b10);  b11 = dot4(c1b, z1b, b11);
        }
        z2[t]             = a00 + b00;
        z2[t + 256]       = a10 + b10;
        z2[512 + t]       = a01 + b01;
        z2[512 + t + 256] = a11 + b11;
    } else {
        // fallback: direct (strided) core rows
        const float4* cr0 = (const float4*)(core + (size_t)t * 512);
        const float4* cr1 = (const float4*)(core + (size_t)(t + 256) * 512);
        const float4* z4 = (const float4*)zz;
        float a0[2] = {0.f, 0.f}, a1[2] = {0.f, 0.f};
        for (int kk = 0; kk < 128; ++kk) {
            const float4 c0 = cr0[kk], c1 = cr1[kk];
            #pragma unroll
            for (int g = 0; g < 2; ++g) {
                const float4 zv = z4[g * 128 + kk];
                a0[g] = dot4(c0, zv, a0[g]);
                a1[g] = dot4(c1, zv, a1[g]);
            }
        }
        #pragma unroll
        for (int g = 0; g < 2; ++g) {
            z2[g * 512 + t]       = a0[g];
            z2[g * 512 + t + 256] = a1[g];
        }
    }
    __syncthreads();

    // of2 rows for this thread's 4 channels (L1-hot global)
    float4 w[4][2];
    {
        const int cc = (4 * t) & 127;
        #pragma unroll
        for (int c = 0; c < 4; ++c) {
            w[c][0] = *(const float4*)(of2 + (cc + c) * 8);
            w[c][1] = *(const float4*)(of2 + (cc + c) * 8 + 4);
        }
    }

    // ---- per-group out-projection + residual + winv + store ----
    float4* out4 = (float4*)out;
    #pragma unroll
    for (int g = 0; g < 2; ++g) {
        // D1: t1[o*64+Bq*8+Cr] = sum_A z2[g][A*64+Bq*8+Cr] * of0T[A][o]
        #pragma unroll
        for (int h = 0; h < 2; ++h) {
            const int id = t + 256 * h;
            const int o = id >> 6, Bq = (id >> 3) & 7, Cr = id & 7;
            float s = 0.f;
            #pragma unroll
            for (int A = 0; A < 8; ++A)
                s = fmaf(z2[g * 512 + A * 64 + Bq * 8 + Cr], s_of0T[A * 8 + o], s);
            t1[id] = s;
        }
        __syncthreads();

        // D2: t2[p*64+o*8+Cr] = sum_B t1[o*64+B*8+Cr] * of1T[B][p]
        #pragma unroll
        for (int h = 0; h < 2; ++h) {
            const int id = t + 256 * h;
            const int p = id >> 6, o = (id >> 3) & 7, Cr = id & 7;
            float s = 0.f;
            #pragma unroll
            for (int B0 = 0; B0 < 8; ++B0) {
                const int Bq = (B0 + o) & 7;          // stagger: 2-way banks
                s = fmaf(t1[o * 64 + Bq * 8 + Cr], s_of1T[Bq * 8 + p], s);
            }
            t2[id] = s;
        }
        __syncthreads();

        // D3: h = v . of2 + residual; * winv; store
        #pragma unroll
        for (int i = 0; i < 8; ++i) {
            const int m = (t >> 5) + 8 * i;
            const int o = m >> 3, p = m & 7;
            const float wv = s_winv[g * 64 + m];
            const int base = p * 64 + o * 8;
            const float4 v0 = *(const float4*)(t2 + base);      // broadcast
            const float4 v1 = *(const float4*)(t2 + base + 4);
            float4 r;
            r.x = dot4(v1, w[0][1], dot4(v0, w[0][0], acc[g][i].x));
            r.y = dot4(v1, w[1][1], dot4(v0, w[1][0], acc[g][i].y));
            r.z = dot4(v1, w[2][1], dot4(v0, w[2][0], acc[g][i].z));
            r.w = dot4(v1, w[3][1], dot4(v0, w[3][0], acc[g][i].w));
            r.x *= wv; r.y *= wv; r.z *= wv; r.w *= wv;
            out4[(size_t)(blk * 2 + g) * 2048 + t + 256 * i] = r;
        }
        __syncthreads();   // before next group's D1 overwrites t1
    }
}

extern "C" void kernel_launch(void* const* d_in, const int* in_sizes, int n_in,
                              void* d_out, int out_size, void* d_ws, size_t ws_size,
                              hipStream_t stream) {
    const float* x    = (const float*)d_in[0];
    const float* core = (const float*)d_in[1];
    const float* of0  = (const float*)d_in[2];
    const float* of1  = (const float*)d_in[3];
    const float* of2  = (const float*)d_in[4];
    const float* if0  = (const float*)d_in[5];
    const float* if1  = (const float*)d_in[6];
    const float* if2  = (const float*)d_in[7];
    const int* mask   = (const int*)d_in[8];
    float* out = (float*)d_out;

    const bool tr = (d_ws != nullptr) && (ws_size >= (size_t)512 * 512 * 4);
    if (tr) {
        float* coreT = (float*)d_ws;
        transpose_core<<<dim3(256), dim3(256), 0, stream>>>(core, coreT);
        noblock_kernel<true><<<dim3(1024), dim3(256), 0, stream>>>(
            x, core, coreT, of0, of1, of2, if0, if1, if2, mask, out);
    } else {
        noblock_kernel<false><<<dim3(1024), dim3(256), 0, stream>>>(
            x, core, core, of0, of1, of2, if0, if1, if2, mask, out);
    }
}